// Round 1
// baseline (588.438 us; speedup 1.0000x reference)
//
#include <hip/hip_runtime.h>
#include <hip/hip_bf16.h>

// Problem constants
#define TT 10000   // time steps (GEMM1 M, output rows)
#define HH 1024    // hidden
#define VV 5000    // visible
#define VP 5120    // visible padded to multiple of 32 (K pad, zero-filled)
#define NSWEEP 6   // fixed-point sweeps; contraction factor ~0.08/sweep

typedef __attribute__((ext_vector_type(8))) short s8v;   // 8 bf16 (4 VGPRs)
typedef __attribute__((ext_vector_type(4))) float f4v;   // MFMA acc

static_assert(sizeof(s8v) == 16, "s8v must be 16B");

__device__ __forceinline__ void async_ld16(void* lds, const void* g) {
  // async global->LDS, 16B per lane; LDS dest is wave-uniform base + lane*16
  __builtin_amdgcn_global_load_lds((__attribute__((address_space(1))) void*)g,
                                   (__attribute__((address_space(3))) void*)lds,
                                   16, 0, 0);
}

__device__ __forceinline__ float sigmoidf_(float x) {
  return 1.0f / (1.0f + __expf(-x));
}

__device__ __forceinline__ unsigned short f2bf_bits(float f) {
  __hip_bfloat16 h = __float2bfloat16(f);
  return *reinterpret_cast<unsigned short*>(&h);
}

// ---------------------------------------------------------------------------
// Transpose + fp32->bf16 convert: in[M][N] fp32 row-major -> out[N][Mp] bf16,
// out[n][m] = (m<M) ? in[m][n] : 0.   (zero-pads M..Mp)
// ---------------------------------------------------------------------------
__global__ void transpose_cvt_kernel(const float* __restrict__ in,
                                     __hip_bfloat16* __restrict__ out,
                                     int M, int N, int Mp) {
  __shared__ float tile[64][65];   // +1 pad: transposed reads conflict-free
  const int m0 = blockIdx.x * 64;  // input-row block (output cols)
  const int n0 = blockIdx.y * 64;  // input-col block (output rows)
  const int tid = threadIdx.x;

#pragma unroll
  for (int it = 0; it < 4; ++it) {
    const int r = (tid >> 4) + it * 16;     // 0..63 input row
    const int c = (tid & 15) * 4;           // 0..60 input col
    const int gm = m0 + r, gn = n0 + c;
    float4 val = make_float4(0.f, 0.f, 0.f, 0.f);
    if (gm < M) {
      if (gn + 3 < N) {
        val = *reinterpret_cast<const float4*>(in + (size_t)gm * N + gn);
      } else {
        float t0 = (gn + 0 < N) ? in[(size_t)gm * N + gn + 0] : 0.f;
        float t1 = (gn + 1 < N) ? in[(size_t)gm * N + gn + 1] : 0.f;
        float t2 = (gn + 2 < N) ? in[(size_t)gm * N + gn + 2] : 0.f;
        float t3 = (gn + 3 < N) ? in[(size_t)gm * N + gn + 3] : 0.f;
        val = make_float4(t0, t1, t2, t3);
      }
    }
    tile[r][c + 0] = val.x; tile[r][c + 1] = val.y;
    tile[r][c + 2] = val.z; tile[r][c + 3] = val.w;
  }
  __syncthreads();

#pragma unroll
  for (int it = 0; it < 4; ++it) {
    const int nr = (tid >> 4) + it * 16;    // output row within tile
    const int mc = (tid & 15) * 4;          // output col within tile
    const int gn = n0 + nr, gm = m0 + mc;
    if (gn < N) {   // gm+3 < Mp always (grid covers Mp exactly)
      union { ushort4 u; unsigned short s[4]; } pk;
      pk.s[0] = f2bf_bits(tile[mc + 0][nr]);
      pk.s[1] = f2bf_bits(tile[mc + 1][nr]);
      pk.s[2] = f2bf_bits(tile[mc + 2][nr]);
      pk.s[3] = f2bf_bits(tile[mc + 3][nr]);
      *reinterpret_cast<ushort4*>(out + (size_t)gn * Mp + gm) = pk.u;
    }
  }
}

// fp32 -> bf16 elementwise (for U; no transpose, row-major preserved)
__global__ void cvt_bf16_kernel(const float* __restrict__ in,
                                __hip_bfloat16* __restrict__ out, int n4) {
  const int i = (blockIdx.x * 256 + threadIdx.x);
  if (i < n4) {
    float4 v = *reinterpret_cast<const float4*>(in + (size_t)i * 4);
    union { ushort4 u; unsigned short s[4]; } pk;
    pk.s[0] = f2bf_bits(v.x); pk.s[1] = f2bf_bits(v.y);
    pk.s[2] = f2bf_bits(v.z); pk.s[3] = f2bf_bits(v.w);
    *reinterpret_cast<ushort4*>(out + (size_t)i * 4) = pk.u;
  }
}

// ---------------------------------------------------------------------------
// bf16 GEMM, C = A(MxK) * Bt(NxK)^T, 128x128 tile, BK=32, 256 thr (4 waves 2x2),
// double-buffered LDS via global_load_lds(16B), counted vmcnt, fused epilogue.
// MODE 0: qout = acc; R0 = sigmoid(acc + (row0? b_init : b_h)); also d_out row0.
// MODE 1: Rout[r+1] = bf16(sigmoid(qin[r+1] + b_h + acc))   (sweep)
// MODE 2: fout[r+1] = sigmoid(qin[r+1] + b_h + acc)         (final sweep, fp32)
// ---------------------------------------------------------------------------
template <int MODE, int K>
__global__ __launch_bounds__(256, 2)
void gemm_bt_kernel(const __hip_bfloat16* __restrict__ A,
                    const __hip_bfloat16* __restrict__ Bt,
                    const float* __restrict__ qin,
                    const float* __restrict__ bh,
                    const float* __restrict__ binit,
                    float* __restrict__ qout,
                    __hip_bfloat16* __restrict__ Rout,
                    __hip_bfloat16* __restrict__ Rrow0,
                    float* __restrict__ fout,
                    int Mclamp /* last valid A row */) {
  constexpr int NK = K / 32;
  __shared__ __align__(16) short As[2 * 128 * 32];
  __shared__ __align__(16) short Bs[2 * 128 * 32];

  const int tid  = threadIdx.x;
  const int wid  = tid >> 6;
  const int lane = tid & 63;
  const int m0 = blockIdx.x * 128;
  const int n0 = blockIdx.y * 128;
  const int wm = wid >> 1, wn = wid & 1;          // 2x2 wave grid, 64x64 each
  const int fr = lane & 15;                       // fragment row/col
  const int fk = (lane >> 4) * 8;                 // fragment k offset

  // staging: wave stages rows [wid*32, wid*32+32); lane -> (row, 16B chunk)
  const int sr = wid * 32 + (lane >> 2);
  const int cb = (lane & 3) * 8;                  // bf16 col offset in tile
  int ar0 = m0 + sr;      if (ar0 > Mclamp) ar0 = Mclamp;
  int ar1 = m0 + sr + 16; if (ar1 > Mclamp) ar1 = Mclamp;
  const int br0 = n0 + sr, br1 = br0 + 16;

  const short* Ag = reinterpret_cast<const short*>(A);
  const short* Bg = reinterpret_cast<const short*>(Bt);

  f4v acc[4][4] = {};

  auto stage = [&](int buf, int kt) {
    const int k0 = kt * 32;
    short* Ad = &As[buf * 4096 + (wid * 32) * 32];
    short* Bd = &Bs[buf * 4096 + (wid * 32) * 32];
    async_ld16(Ad,           Ag + (size_t)ar0 * K + k0 + cb);
    async_ld16(Ad + 16 * 32, Ag + (size_t)ar1 * K + k0 + cb);
    async_ld16(Bd,           Bg + (size_t)br0 * K + k0 + cb);
    async_ld16(Bd + 16 * 32, Bg + (size_t)br1 * K + k0 + cb);
  };

  stage(0, 0);
  int cur = 0;
  for (int kt = 0; kt < NK; ++kt) {
    if (kt + 1 < NK) {
      stage(cur ^ 1, kt + 1);                       // 4 more loads in flight
      asm volatile("s_waitcnt vmcnt(4)" ::: "memory");  // cur's 4 complete
    } else {
      asm volatile("s_waitcnt vmcnt(0)" ::: "memory");
    }
    __builtin_amdgcn_s_barrier();

    const short* Ab = &As[cur * 4096];
    const short* Bb = &Bs[cur * 4096];
    s8v af[4], bfv[4];
#pragma unroll
    for (int m = 0; m < 4; ++m)
      af[m] = *reinterpret_cast<const s8v*>(&Ab[(wm * 64 + m * 16 + fr) * 32 + fk]);
#pragma unroll
    for (int n = 0; n < 4; ++n)
      bfv[n] = *reinterpret_cast<const s8v*>(&Bb[(wn * 64 + n * 16 + fr) * 32 + fk]);
#pragma unroll
    for (int m = 0; m < 4; ++m)
#pragma unroll
      for (int n = 0; n < 4; ++n)
        acc[m][n] = __builtin_amdgcn_mfma_f32_16x16x32_bf16(af[m], bfv[n], acc[m][n], 0, 0, 0);

    __builtin_amdgcn_s_barrier();   // readers done before next stage overwrites
    cur ^= 1;
  }

  // Epilogue. C/D layout: col = lane&15, row = (lane>>4)*4 + reg  [m89-verified]
  const int rbase = wm * 64 + (lane >> 4) * 4;
  const int cbase = n0 + wn * 64 + fr;
#pragma unroll
  for (int m = 0; m < 4; ++m) {
#pragma unroll
    for (int n = 0; n < 4; ++n) {
      const int gc = cbase + n * 16;
#pragma unroll
      for (int j = 0; j < 4; ++j) {
        const int gr = m0 + rbase + m * 16 + j;
        const float val = acc[m][n][j];
        if constexpr (MODE == 0) {
          if (gr < TT) {
            qout[gr * HH + gc] = val;
            const float bias = (gr == 0) ? binit[gc] : bh[gc];
            const float r = sigmoidf_(val + bias);
            Rout[gr * HH + gc] = __float2bfloat16(r);
            if (gr == 0) {
              Rrow0[gc] = __float2bfloat16(r);  // row 0 into 2nd ping-pong buf
              fout[gc] = r;                     // d_out row 0 (exact, fixed)
            }
          }
        } else {
          const int orow = gr + 1;              // A row gr feeds output row gr+1
          if (orow < TT) {
            const float r = sigmoidf_(qin[orow * HH + gc] + bh[gc] + val);
            if constexpr (MODE == 1) Rout[orow * HH + gc] = __float2bfloat16(r);
            else                     fout[orow * HH + gc] = r;
          }
        }
      }
    }
  }
}

// ---------------------------------------------------------------------------
extern "C" void kernel_launch(void* const* d_in, const int* in_sizes, int n_in,
                              void* d_out, int out_size, void* d_ws, size_t ws_size,
                              hipStream_t stream) {
  const float* v     = (const float*)d_in[0];  // (V, T)
  const float* W     = (const float*)d_in[1];  // (V, H)
  const float* U     = (const float*)d_in[2];  // (H, H)
  const float* b_h   = (const float*)d_in[4];  // (H,)
  const float* b_ini = (const float*)d_in[5];  // (H,)
  float* out = (float*)d_out;                  // (T, H) fp32

  // Workspace layout (all region sizes multiples of 16B): ~188 MiB total
  char* p = (char*)d_ws;
  __hip_bfloat16* vT = (__hip_bfloat16*)p; p += (size_t)TT * VP * 2;  // 102.4 MB
  __hip_bfloat16* Wt = (__hip_bfloat16*)p; p += (size_t)HH * VP * 2;  //  10.5 MB
  __hip_bfloat16* Ub = (__hip_bfloat16*)p; p += (size_t)HH * HH * 2;  //   2.1 MB
  float*          q  = (float*)p;          p += (size_t)TT * HH * 4;  //  41.0 MB
  __hip_bfloat16* Ra = (__hip_bfloat16*)p; p += (size_t)TT * HH * 2;  //  20.5 MB
  __hip_bfloat16* Rb = (__hip_bfloat16*)p; p += (size_t)TT * HH * 2;  //  20.5 MB

  // 1) vT[t][vi] = v[vi][t] (bf16, K zero-padded to VP)
  transpose_cvt_kernel<<<dim3(VP / 64, (TT + 63) / 64), 256, 0, stream>>>(
      v, vT, VV, TT, VP);
  // 2) Wt[h][vi] = W[vi][h] (bf16, zero-padded)
  transpose_cvt_kernel<<<dim3(VP / 64, HH / 64), 256, 0, stream>>>(
      W, Wt, VV, HH, VP);
  // 3) U -> bf16 (row-major kept: Bt[h][j] = U[h][j], exactly what's needed)
  cvt_bf16_kernel<<<(HH * HH / 4 + 255) / 256, 256, 0, stream>>>(U, Ub, HH * HH / 4);

  const dim3 gg((TT + 127) / 128, HH / 128);  // 79 x 8

  // 4) GEMM1: q = vT @ Wt^T; R^(0) = sigmoid(q + bias); d_out row 0
  gemm_bt_kernel<0, VP><<<gg, 256, 0, stream>>>(
      vT, Wt, nullptr, b_h, b_ini, q, Ra, Rb, out, TT - 1);

  // 5) fixed-point sweeps: R <- sigmoid(q + b_h + shift(R) @ U^T)
  const __hip_bfloat16* rin = Ra;
  __hip_bfloat16* rout = Rb;
  for (int s = 1; s < NSWEEP; ++s) {
    gemm_bt_kernel<1, HH><<<gg, 256, 0, stream>>>(
        rin, Ub, q, b_h, nullptr, nullptr, rout, nullptr, nullptr, TT - 2);
    const __hip_bfloat16* t = rin; rin = rout; rout = (__hip_bfloat16*)t;
  }
  // 6) final sweep writes fp32 rows 1..T-1 of d_out
  gemm_bt_kernel<2, HH><<<gg, 256, 0, stream>>>(
      rin, Ub, q, b_h, nullptr, nullptr, nullptr, nullptr, out, TT - 2);

  (void)in_sizes; (void)n_in; (void)out_size; (void)ws_size;
}

// Round 2
// 458.327 us; speedup vs baseline: 1.2839x; 1.2839x over previous
//
#include <hip/hip_runtime.h>
#include <hip/hip_bf16.h>

// Problem constants
#define TT 10000   // time steps (GEMM1 M, output rows)
#define HH 1024    // hidden
#define VV 5000    // visible
#define VP 5120    // visible padded to multiple of 32 (K pad, zero-filled)
#define NREFINE 4  // fixed-point refinement sweeps after R0; contraction ~0.08/sweep

typedef __attribute__((ext_vector_type(8))) short s8v;   // 8 bf16 (4 VGPRs)
typedef __attribute__((ext_vector_type(4))) float f4v;   // MFMA acc

static_assert(sizeof(s8v) == 16, "s8v must be 16B");

__device__ __forceinline__ void async_ld16(void* lds, const void* g) {
  // async global->LDS, 16B per lane; LDS dest is wave-uniform base + lane*16
  __builtin_amdgcn_global_load_lds((__attribute__((address_space(1))) void*)g,
                                   (__attribute__((address_space(3))) void*)lds,
                                   16, 0, 0);
}

__device__ __forceinline__ float sigmoidf_(float x) {
  return 1.0f / (1.0f + __expf(-x));
}

__device__ __forceinline__ unsigned short f2bf_bits(float f) {
  __hip_bfloat16 h = __float2bfloat16(f);
  return *reinterpret_cast<unsigned short*>(&h);
}

// ---------------------------------------------------------------------------
// Transpose + fp32->bf16 convert: in[M][N] fp32 row-major -> out[N][Mp] bf16,
// out[n][m] = (m<M) ? in[m][n] : 0.   (zero-pads M..Mp)
// ---------------------------------------------------------------------------
__global__ void transpose_cvt_kernel(const float* __restrict__ in,
                                     __hip_bfloat16* __restrict__ out,
                                     int M, int N, int Mp) {
  __shared__ float tile[64][65];   // +1 pad: transposed reads conflict-free
  const int m0 = blockIdx.x * 64;  // input-row block (output cols)
  const int n0 = blockIdx.y * 64;  // input-col block (output rows)
  const int tid = threadIdx.x;

#pragma unroll
  for (int it = 0; it < 4; ++it) {
    const int r = (tid >> 4) + it * 16;     // 0..63 input row
    const int c = (tid & 15) * 4;           // 0..60 input col
    const int gm = m0 + r, gn = n0 + c;
    float4 val = make_float4(0.f, 0.f, 0.f, 0.f);
    if (gm < M) {
      if (gn + 3 < N) {
        val = *reinterpret_cast<const float4*>(in + (size_t)gm * N + gn);
      } else {
        float t0 = (gn + 0 < N) ? in[(size_t)gm * N + gn + 0] : 0.f;
        float t1 = (gn + 1 < N) ? in[(size_t)gm * N + gn + 1] : 0.f;
        float t2 = (gn + 2 < N) ? in[(size_t)gm * N + gn + 2] : 0.f;
        float t3 = (gn + 3 < N) ? in[(size_t)gm * N + gn + 3] : 0.f;
        val = make_float4(t0, t1, t2, t3);
      }
    }
    tile[r][c + 0] = val.x; tile[r][c + 1] = val.y;
    tile[r][c + 2] = val.z; tile[r][c + 3] = val.w;
  }
  __syncthreads();

#pragma unroll
  for (int it = 0; it < 4; ++it) {
    const int nr = (tid >> 4) + it * 16;    // output row within tile
    const int mc = (tid & 15) * 4;          // output col within tile
    const int gn = n0 + nr, gm = m0 + mc;
    if (gn < N) {   // gm+3 < Mp always (grid covers Mp exactly)
      union { ushort4 u; unsigned short s[4]; } pk;
      pk.s[0] = f2bf_bits(tile[mc + 0][nr]);
      pk.s[1] = f2bf_bits(tile[mc + 1][nr]);
      pk.s[2] = f2bf_bits(tile[mc + 2][nr]);
      pk.s[3] = f2bf_bits(tile[mc + 3][nr]);
      *reinterpret_cast<ushort4*>(out + (size_t)gn * Mp + gm) = pk.u;
    }
  }
}

// fp32 -> bf16 elementwise (for U; no transpose, row-major preserved)
__global__ void cvt_bf16_kernel(const float* __restrict__ in,
                                __hip_bfloat16* __restrict__ out, int n4) {
  const int i = (blockIdx.x * 256 + threadIdx.x);
  if (i < n4) {
    float4 v = *reinterpret_cast<const float4*>(in + (size_t)i * 4);
    union { ushort4 u; unsigned short s[4]; } pk;
    pk.s[0] = f2bf_bits(v.x); pk.s[1] = f2bf_bits(v.y);
    pk.s[2] = f2bf_bits(v.z); pk.s[3] = f2bf_bits(v.w);
    *reinterpret_cast<ushort4*>(out + (size_t)i * 4) = pk.u;
  }
}

// ---------------------------------------------------------------------------
// bf16 GEMM, C = A(MxK) * Bt(NxK)^T, 128x128 tile, BK=32, 256 thr (4 waves 2x2),
// double-buffered LDS via global_load_lds(16B), counted vmcnt, fused epilogue.
// Grid is (N/128, M/128): N-block on blockIdx.x so XCD = bid%8 = n-block ->
// each XCD's B panel is L2-resident; A re-reads served by shared L3.
// MODE 0: qb = bf16(acc + bias); R0 = sigmoid(acc + bias); d_out row 0.
// MODE 1: Rout[r+1] = bf16(sigmoid(qb[r+1] + acc))   (sweep)
// MODE 2: fout[r+1] = sigmoid(qb[r+1] + acc)         (final sweep, fp32)
// ---------------------------------------------------------------------------
template <int MODE, int K>
__global__ __launch_bounds__(256, 2)
void gemm_bt_kernel(const __hip_bfloat16* __restrict__ A,
                    const __hip_bfloat16* __restrict__ Bt,
                    const __hip_bfloat16* __restrict__ qb_in,
                    const float* __restrict__ bh,
                    const float* __restrict__ binit,
                    __hip_bfloat16* __restrict__ qb_out,
                    __hip_bfloat16* __restrict__ Rout,
                    __hip_bfloat16* __restrict__ Rrow0,
                    float* __restrict__ fout,
                    int Mclamp /* last valid A row */) {
  constexpr int NK = K / 32;
  __shared__ __align__(16) short As[2 * 128 * 32];
  __shared__ __align__(16) short Bs[2 * 128 * 32];

  const int tid  = threadIdx.x;
  const int wid  = tid >> 6;
  const int lane = tid & 63;
  const int m0 = blockIdx.y * 128;    // M-block (slow)
  const int n0 = blockIdx.x * 128;    // N-block (fast; = XCD id)
  const int wm = wid >> 1, wn = wid & 1;          // 2x2 wave grid, 64x64 each
  const int fr = lane & 15;                       // fragment row/col
  const int fk = (lane >> 4) * 8;                 // fragment k offset

  // staging: wave stages rows [wid*32, wid*32+32); lane -> (row, 16B chunk)
  const int sr = wid * 32 + (lane >> 2);
  const int cb = (lane & 3) * 8;                  // bf16 col offset in tile
  int ar0 = m0 + sr;      if (ar0 > Mclamp) ar0 = Mclamp;
  int ar1 = m0 + sr + 16; if (ar1 > Mclamp) ar1 = Mclamp;
  const int br0 = n0 + sr, br1 = br0 + 16;

  const short* Ag = reinterpret_cast<const short*>(A);
  const short* Bg = reinterpret_cast<const short*>(Bt);

  f4v acc[4][4] = {};

  auto stage = [&](int buf, int kt) {
    const int k0 = kt * 32;
    short* Ad = &As[buf * 4096 + (wid * 32) * 32];
    short* Bd = &Bs[buf * 4096 + (wid * 32) * 32];
    async_ld16(Ad,           Ag + (size_t)ar0 * K + k0 + cb);
    async_ld16(Ad + 16 * 32, Ag + (size_t)ar1 * K + k0 + cb);
    async_ld16(Bd,           Bg + (size_t)br0 * K + k0 + cb);
    async_ld16(Bd + 16 * 32, Bg + (size_t)br1 * K + k0 + cb);
  };

  stage(0, 0);
  int cur = 0;
  for (int kt = 0; kt < NK; ++kt) {
    if (kt + 1 < NK) {
      stage(cur ^ 1, kt + 1);                       // 4 more loads in flight
      asm volatile("s_waitcnt vmcnt(4)" ::: "memory");  // cur's 4 complete
    } else {
      asm volatile("s_waitcnt vmcnt(0)" ::: "memory");
    }
    __builtin_amdgcn_s_barrier();

    const short* Ab = &As[cur * 4096];
    const short* Bb = &Bs[cur * 4096];
    s8v af[4], bfv[4];
#pragma unroll
    for (int m = 0; m < 4; ++m)
      af[m] = *reinterpret_cast<const s8v*>(&Ab[(wm * 64 + m * 16 + fr) * 32 + fk]);
#pragma unroll
    for (int n = 0; n < 4; ++n)
      bfv[n] = *reinterpret_cast<const s8v*>(&Bb[(wn * 64 + n * 16 + fr) * 32 + fk]);
#pragma unroll
    for (int m = 0; m < 4; ++m)
#pragma unroll
      for (int n = 0; n < 4; ++n)
        acc[m][n] = __builtin_amdgcn_mfma_f32_16x16x32_bf16(af[m], bfv[n], acc[m][n], 0, 0, 0);

    __builtin_amdgcn_s_barrier();   // readers done before next stage overwrites
    cur ^= 1;
  }

  // Epilogue. C/D layout: col = lane&15, row = (lane>>4)*4 + reg  [m89-verified]
  const int rbase = wm * 64 + (lane >> 4) * 4;
  const int cbase = n0 + wn * 64 + fr;
#pragma unroll
  for (int m = 0; m < 4; ++m) {
#pragma unroll
    for (int n = 0; n < 4; ++n) {
      const int gc = cbase + n * 16;
#pragma unroll
      for (int j = 0; j < 4; ++j) {
        const int gr = m0 + rbase + m * 16 + j;
        const float val = acc[m][n][j];
        if constexpr (MODE == 0) {
          if (gr < TT) {
            const float bias = (gr == 0) ? binit[gc] : bh[gc];
            const float pre = val + bias;        // q + bias, pre-fused
            qb_out[gr * HH + gc] = __float2bfloat16(pre);
            const float r = sigmoidf_(pre);
            Rout[gr * HH + gc] = __float2bfloat16(r);
            if (gr == 0) {
              Rrow0[gc] = __float2bfloat16(r);  // row 0 into 2nd ping-pong buf
              fout[gc] = r;                     // d_out row 0 (exact, fixed)
            }
          }
        } else {
          const int orow = gr + 1;              // A row gr feeds output row gr+1
          if (orow < TT) {
            const float pre = __bfloat162float(qb_in[orow * HH + gc]) + val;
            const float r = sigmoidf_(pre);
            if constexpr (MODE == 1) Rout[orow * HH + gc] = __float2bfloat16(r);
            else                     fout[orow * HH + gc] = r;
          }
        }
      }
    }
  }
}

// ---------------------------------------------------------------------------
extern "C" void kernel_launch(void* const* d_in, const int* in_sizes, int n_in,
                              void* d_out, int out_size, void* d_ws, size_t ws_size,
                              hipStream_t stream) {
  const float* v     = (const float*)d_in[0];  // (V, T)
  const float* W     = (const float*)d_in[1];  // (V, H)
  const float* U     = (const float*)d_in[2];  // (H, H)
  const float* b_h   = (const float*)d_in[4];  // (H,)
  const float* b_ini = (const float*)d_in[5];  // (H,)
  float* out = (float*)d_out;                  // (T, H) fp32

  // Workspace layout (all region sizes multiples of 16B): ~177 MiB total
  char* p = (char*)d_ws;
  __hip_bfloat16* vT = (__hip_bfloat16*)p; p += (size_t)TT * VP * 2;  // 102.4 MB
  __hip_bfloat16* Wt = (__hip_bfloat16*)p; p += (size_t)HH * VP * 2;  //  10.5 MB
  __hip_bfloat16* Ub = (__hip_bfloat16*)p; p += (size_t)HH * HH * 2;  //   2.1 MB
  __hip_bfloat16* qb = (__hip_bfloat16*)p; p += (size_t)TT * HH * 2;  //  20.5 MB
  __hip_bfloat16* Ra = (__hip_bfloat16*)p; p += (size_t)TT * HH * 2;  //  20.5 MB
  __hip_bfloat16* Rb = (__hip_bfloat16*)p; p += (size_t)TT * HH * 2;  //  20.5 MB

  // 1) vT[t][vi] = v[vi][t] (bf16, K zero-padded to VP)
  transpose_cvt_kernel<<<dim3(VP / 64, (TT + 63) / 64), 256, 0, stream>>>(
      v, vT, VV, TT, VP);
  // 2) Wt[h][vi] = W[vi][h] (bf16, zero-padded)
  transpose_cvt_kernel<<<dim3(VP / 64, HH / 64), 256, 0, stream>>>(
      W, Wt, VV, HH, VP);
  // 3) U -> bf16 (row-major kept: Bt[h][j] = U[h][j], exactly what's needed)
  cvt_bf16_kernel<<<(HH * HH / 4 + 255) / 256, 256, 0, stream>>>(U, Ub, HH * HH / 4);

  const dim3 gg(HH / 128, (TT + 127) / 128);  // (8 N, 79 M): N fastest -> XCD=n

  // 4) GEMM1: q = vT @ Wt^T; qb = bf16(q+bias); R^(0) = sigmoid(q+bias); out row 0
  gemm_bt_kernel<0, VP><<<gg, 256, 0, stream>>>(
      vT, Wt, nullptr, b_h, b_ini, qb, Ra, Rb, out, TT - 1);

  // 5) fixed-point sweeps: R <- sigmoid(qb + shift(R) @ U^T)
  const __hip_bfloat16* rin = Ra;
  __hip_bfloat16* rout = Rb;
  for (int s = 1; s < NREFINE; ++s) {
    gemm_bt_kernel<1, HH><<<gg, 256, 0, stream>>>(
        rin, Ub, qb, nullptr, nullptr, nullptr, rout, nullptr, nullptr, TT - 2);
    const __hip_bfloat16* t = rin; rin = rout; rout = (__hip_bfloat16*)t;
  }
  // 6) final sweep writes fp32 rows 1..T-1 of d_out
  gemm_bt_kernel<2, HH><<<gg, 256, 0, stream>>>(
      rin, Ub, qb, nullptr, nullptr, nullptr, nullptr, nullptr, out, TT - 2);

  (void)in_sizes; (void)n_in; (void)out_size; (void)ws_size;
}

// Round 3
// 371.164 us; speedup vs baseline: 1.5854x; 1.2348x over previous
//
#include <hip/hip_runtime.h>
#include <hip/hip_bf16.h>

// Problem constants
#define TT 10000   // time steps (GEMM1 M, output rows)
#define HH 1024    // hidden
#define VV 5000    // visible
#define VP 5120    // visible padded to multiple of 32 (K pad, zero-filled)
#define NREFINE 3  // refinement sweeps after R0 (2x bf16 + 1x fp32 final)

typedef __attribute__((ext_vector_type(8))) short s8v;   // 8 bf16 (4 VGPRs)
typedef __attribute__((ext_vector_type(4))) float f4v;   // MFMA acc

static_assert(sizeof(s8v) == 16, "s8v must be 16B");

__device__ __forceinline__ void async_ld16(void* lds, const void* g) {
  // async global->LDS, 16B per lane; LDS dest is wave-uniform base + lane*16
  __builtin_amdgcn_global_load_lds((__attribute__((address_space(1))) void*)g,
                                   (__attribute__((address_space(3))) void*)lds,
                                   16, 0, 0);
}

__device__ __forceinline__ float sigmoidf_(float x) {
  return 1.0f / (1.0f + __expf(-x));
}

__device__ __forceinline__ unsigned short f2bf_bits(float f) {
  __hip_bfloat16 h = __float2bfloat16(f);
  return *reinterpret_cast<unsigned short*>(&h);
}

// ---------------------------------------------------------------------------
// Transpose + fp32->bf16 convert: in[M][N] fp32 row-major -> out[N][Mp] bf16,
// out[n][m] = (m<M) ? in[m][n] : 0.   (zero-pads M..Mp)
// ---------------------------------------------------------------------------
__global__ void transpose_cvt_kernel(const float* __restrict__ in,
                                     __hip_bfloat16* __restrict__ out,
                                     int M, int N, int Mp) {
  __shared__ float tile[64][65];   // +1 pad: transposed reads conflict-free
  const int m0 = blockIdx.x * 64;  // input-row block (output cols)
  const int n0 = blockIdx.y * 64;  // input-col block (output rows)
  const int tid = threadIdx.x;

#pragma unroll
  for (int it = 0; it < 4; ++it) {
    const int r = (tid >> 4) + it * 16;     // 0..63 input row
    const int c = (tid & 15) * 4;           // 0..60 input col
    const int gm = m0 + r, gn = n0 + c;
    float4 val = make_float4(0.f, 0.f, 0.f, 0.f);
    if (gm < M) {
      if (gn + 3 < N) {
        val = *reinterpret_cast<const float4*>(in + (size_t)gm * N + gn);
      } else {
        float t0 = (gn + 0 < N) ? in[(size_t)gm * N + gn + 0] : 0.f;
        float t1 = (gn + 1 < N) ? in[(size_t)gm * N + gn + 1] : 0.f;
        float t2 = (gn + 2 < N) ? in[(size_t)gm * N + gn + 2] : 0.f;
        float t3 = (gn + 3 < N) ? in[(size_t)gm * N + gn + 3] : 0.f;
        val = make_float4(t0, t1, t2, t3);
      }
    }
    tile[r][c + 0] = val.x; tile[r][c + 1] = val.y;
    tile[r][c + 2] = val.z; tile[r][c + 3] = val.w;
  }
  __syncthreads();

#pragma unroll
  for (int it = 0; it < 4; ++it) {
    const int nr = (tid >> 4) + it * 16;    // output row within tile
    const int mc = (tid & 15) * 4;          // output col within tile
    const int gn = n0 + nr, gm = m0 + mc;
    if (gn < N) {   // gm+3 < Mp always (grid covers Mp exactly)
      union { ushort4 u; unsigned short s[4]; } pk;
      pk.s[0] = f2bf_bits(tile[mc + 0][nr]);
      pk.s[1] = f2bf_bits(tile[mc + 1][nr]);
      pk.s[2] = f2bf_bits(tile[mc + 2][nr]);
      pk.s[3] = f2bf_bits(tile[mc + 3][nr]);
      *reinterpret_cast<ushort4*>(out + (size_t)gn * Mp + gm) = pk.u;
    }
  }
}

// fp32 -> bf16 elementwise (for U; no transpose, row-major preserved)
__global__ void cvt_bf16_kernel(const float* __restrict__ in,
                                __hip_bfloat16* __restrict__ out, int n4) {
  const int i = (blockIdx.x * 256 + threadIdx.x);
  if (i < n4) {
    float4 v = *reinterpret_cast<const float4*>(in + (size_t)i * 4);
    union { ushort4 u; unsigned short s[4]; } pk;
    pk.s[0] = f2bf_bits(v.x); pk.s[1] = f2bf_bits(v.y);
    pk.s[2] = f2bf_bits(v.z); pk.s[3] = f2bf_bits(v.w);
    *reinterpret_cast<ushort4*>(out + (size_t)i * 4) = pk.u;
  }
}

// ---------------------------------------------------------------------------
// bf16 GEMM, C = A(MxK) * Bt(NxK)^T, 128x128 tile, BK=32, 256 thr (4 waves 2x2),
// double-buffered LDS via global_load_lds(16B), counted vmcnt, fused epilogue.
//
// Grid is (8 n-blocks, 79 m-blocks). XCD swizzle (M-chunked, bijective):
// linear wg id orig = bx + 8*by round-robins over XCDs (xcd = orig%8), so we
// transpose: wgid = xcd*79 + orig/8. XCD x then owns a CONTIGUOUS ~10-m-block
// slice across ALL n -> its unique working set (A-slice ~13MB + B panel) is
// L2/L3-resident; A is fetched from HBM once chip-wide instead of 8x.
//
// MODE 0: qb = bf16(acc + bias); R0 = sigmoid(acc + bias); d_out row 0.
// MODE 1: Rout[r+1] = bf16(sigmoid(qb[r+1] + acc))   (sweep)
// MODE 2: fout[r+1] = sigmoid(qb[r+1] + acc)         (final sweep, fp32)
// ---------------------------------------------------------------------------
template <int MODE, int K>
__global__ __launch_bounds__(256, 4)   // 4 blocks/CU (LDS 32KB, VGPR<=128)
void gemm_bt_kernel(const __hip_bfloat16* __restrict__ A,
                    const __hip_bfloat16* __restrict__ Bt,
                    const __hip_bfloat16* __restrict__ qb_in,
                    const float* __restrict__ bh,
                    const float* __restrict__ binit,
                    __hip_bfloat16* __restrict__ qb_out,
                    __hip_bfloat16* __restrict__ Rout,
                    __hip_bfloat16* __restrict__ Rrow0,
                    float* __restrict__ fout,
                    int Mclamp /* last valid A row */) {
  constexpr int NK = K / 32;
  __shared__ __align__(16) short As[2 * 128 * 32];
  __shared__ __align__(16) short Bs[2 * 128 * 32];

  const int tid  = threadIdx.x;
  const int wid  = tid >> 6;
  const int lane = tid & 63;

  // M-chunked bijective XCD swizzle (grid must be 8 x GY)
  const int GY   = gridDim.y;
  const int orig = blockIdx.x + (blockIdx.y << 3);
  const int wgid = (orig & 7) * GY + (orig >> 3);
  const int n0 = (wgid & 7) * 128;    // n-block cycles fast within an XCD
  const int m0 = (wgid >> 3) * 128;   // contiguous m-slice per XCD

  const int wm = wid >> 1, wn = wid & 1;          // 2x2 wave grid, 64x64 each
  const int fr = lane & 15;                       // fragment row/col
  const int fk = (lane >> 4) * 8;                 // fragment k offset

  // staging: wave stages rows [wid*32, wid*32+32); lane -> (row, 16B chunk)
  const int sr = wid * 32 + (lane >> 2);
  const int cb = (lane & 3) * 8;                  // bf16 col offset in tile
  int ar0 = m0 + sr;      if (ar0 > Mclamp) ar0 = Mclamp;
  int ar1 = m0 + sr + 16; if (ar1 > Mclamp) ar1 = Mclamp;
  const int br0 = n0 + sr, br1 = br0 + 16;

  const short* Ag = reinterpret_cast<const short*>(A);
  const short* Bg = reinterpret_cast<const short*>(Bt);

  f4v acc[4][4] = {};

  auto stage = [&](int buf, int kt) {
    const int k0 = kt * 32;
    short* Ad = &As[buf * 4096 + (wid * 32) * 32];
    short* Bd = &Bs[buf * 4096 + (wid * 32) * 32];
    async_ld16(Ad,           Ag + (size_t)ar0 * K + k0 + cb);
    async_ld16(Ad + 16 * 32, Ag + (size_t)ar1 * K + k0 + cb);
    async_ld16(Bd,           Bg + (size_t)br0 * K + k0 + cb);
    async_ld16(Bd + 16 * 32, Bg + (size_t)br1 * K + k0 + cb);
  };

  stage(0, 0);
  int cur = 0;
  for (int kt = 0; kt < NK; ++kt) {
    if (kt + 1 < NK) {
      stage(cur ^ 1, kt + 1);                       // 4 more loads in flight
      asm volatile("s_waitcnt vmcnt(4)" ::: "memory");  // cur's 4 complete
    } else {
      asm volatile("s_waitcnt vmcnt(0)" ::: "memory");
    }
    __builtin_amdgcn_s_barrier();

    const short* Ab = &As[cur * 4096];
    const short* Bb = &Bs[cur * 4096];
    s8v af[4], bfv[4];
#pragma unroll
    for (int m = 0; m < 4; ++m)
      af[m] = *reinterpret_cast<const s8v*>(&Ab[(wm * 64 + m * 16 + fr) * 32 + fk]);
#pragma unroll
    for (int n = 0; n < 4; ++n)
      bfv[n] = *reinterpret_cast<const s8v*>(&Bb[(wn * 64 + n * 16 + fr) * 32 + fk]);
#pragma unroll
    for (int m = 0; m < 4; ++m)
#pragma unroll
      for (int n = 0; n < 4; ++n)
        acc[m][n] = __builtin_amdgcn_mfma_f32_16x16x32_bf16(af[m], bfv[n], acc[m][n], 0, 0, 0);

    __builtin_amdgcn_s_barrier();   // readers done before next stage overwrites
    cur ^= 1;
  }

  // Epilogue. C/D layout: col = lane&15, row = (lane>>4)*4 + reg  [m89-verified]
  const int rbase = wm * 64 + (lane >> 4) * 4;
  const int cbase = n0 + wn * 64 + fr;
#pragma unroll
  for (int m = 0; m < 4; ++m) {
#pragma unroll
    for (int n = 0; n < 4; ++n) {
      const int gc = cbase + n * 16;
#pragma unroll
      for (int j = 0; j < 4; ++j) {
        const int gr = m0 + rbase + m * 16 + j;
        const float val = acc[m][n][j];
        if constexpr (MODE == 0) {
          if (gr < TT) {
            const float bias = (gr == 0) ? binit[gc] : bh[gc];
            const float pre = val + bias;        // q + bias, pre-fused
            qb_out[gr * HH + gc] = __float2bfloat16(pre);
            const float r = sigmoidf_(pre);
            Rout[gr * HH + gc] = __float2bfloat16(r);
            if (gr == 0) {
              Rrow0[gc] = __float2bfloat16(r);  // row 0 into 2nd ping-pong buf
              fout[gc] = r;                     // d_out row 0 (exact, fixed)
            }
          }
        } else {
          const int orow = gr + 1;              // A row gr feeds output row gr+1
          if (orow < TT) {
            const float pre = __bfloat162float(qb_in[orow * HH + gc]) + val;
            const float r = sigmoidf_(pre);
            if constexpr (MODE == 1) Rout[orow * HH + gc] = __float2bfloat16(r);
            else                     fout[orow * HH + gc] = r;
          }
        }
      }
    }
  }
}

// ---------------------------------------------------------------------------
extern "C" void kernel_launch(void* const* d_in, const int* in_sizes, int n_in,
                              void* d_out, int out_size, void* d_ws, size_t ws_size,
                              hipStream_t stream) {
  const float* v     = (const float*)d_in[0];  // (V, T)
  const float* W     = (const float*)d_in[1];  // (V, H)
  const float* U     = (const float*)d_in[2];  // (H, H)
  const float* b_h   = (const float*)d_in[4];  // (H,)
  const float* b_ini = (const float*)d_in[5];  // (H,)
  float* out = (float*)d_out;                  // (T, H) fp32

  // Workspace layout (all region sizes multiples of 16B): ~177 MiB total
  char* p = (char*)d_ws;
  __hip_bfloat16* vT = (__hip_bfloat16*)p; p += (size_t)TT * VP * 2;  // 102.4 MB
  __hip_bfloat16* Wt = (__hip_bfloat16*)p; p += (size_t)HH * VP * 2;  //  10.5 MB
  __hip_bfloat16* Ub = (__hip_bfloat16*)p; p += (size_t)HH * HH * 2;  //   2.1 MB
  __hip_bfloat16* qb = (__hip_bfloat16*)p; p += (size_t)TT * HH * 2;  //  20.5 MB
  __hip_bfloat16* Ra = (__hip_bfloat16*)p; p += (size_t)TT * HH * 2;  //  20.5 MB
  __hip_bfloat16* Rb = (__hip_bfloat16*)p; p += (size_t)TT * HH * 2;  //  20.5 MB

  // 1) vT[t][vi] = v[vi][t] (bf16, K zero-padded to VP)
  transpose_cvt_kernel<<<dim3(VP / 64, (TT + 63) / 64), 256, 0, stream>>>(
      v, vT, VV, TT, VP);
  // 2) Wt[h][vi] = W[vi][h] (bf16, zero-padded)
  transpose_cvt_kernel<<<dim3(VP / 64, HH / 64), 256, 0, stream>>>(
      W, Wt, VV, HH, VP);
  // 3) U -> bf16 (row-major kept: Bt[h][j] = U[h][j], exactly what's needed)
  cvt_bf16_kernel<<<(HH * HH / 4 + 255) / 256, 256, 0, stream>>>(U, Ub, HH * HH / 4);

  const dim3 gg(HH / 128, (TT + 127) / 128);  // (8 n, 79 m); swizzled in-kernel

  // 4) GEMM1: q = vT @ Wt^T; qb = bf16(q+bias); R^(0) = sigmoid(q+bias); out row 0
  gemm_bt_kernel<0, VP><<<gg, 256, 0, stream>>>(
      vT, Wt, nullptr, b_h, b_ini, qb, Ra, Rb, out, TT - 1);

  // 5) fixed-point sweeps: R <- sigmoid(qb + shift(R) @ U^T)
  const __hip_bfloat16* rin = Ra;
  __hip_bfloat16* rout = Rb;
  for (int s = 1; s < NREFINE; ++s) {
    gemm_bt_kernel<1, HH><<<gg, 256, 0, stream>>>(
        rin, Ub, qb, nullptr, nullptr, nullptr, rout, nullptr, nullptr, TT - 2);
    const __hip_bfloat16* t = rin; rin = rout; rout = (__hip_bfloat16*)t;
  }
  // 6) final sweep writes fp32 rows 1..T-1 of d_out
  gemm_bt_kernel<2, HH><<<gg, 256, 0, stream>>>(
      rin, Ub, qb, nullptr, nullptr, nullptr, nullptr, nullptr, out, TT - 2);

  (void)in_sizes; (void)n_in; (void)out_size; (void)ws_size;
}